// Round 6
// baseline (201.530 us; speedup 1.0000x reference)
//
#include <hip/hip_runtime.h>
#include <math.h>

#define Himg 128
#define Wimg 128
#define HW   16384      // 128*128
#define Cin  64
#define Kk   9
#define OUTC 128
#define Bsz  8

typedef __attribute__((ext_vector_type(8))) _Float16 half8;
typedef __attribute__((ext_vector_type(4))) float   floatx4;

#define SPL8(v) ((half8){(v),(v),(v),(v),(v),(v),(v),(v)})

// ---------------------------------------------------------------------------
// fused prep kernel:
//   blocks    0..1023 : transpose+convert x[b][c][h][w] f32 -> xt[b][h][w][c] f16
//   blocks 1024..1311 : repack w_conv into MFMA-fragment order (wpk_h)
//   blocks 1312..1383 : repack w_offset/w_mask into fragment order (wpk2)
// ---------------------------------------------------------------------------
__global__ __launch_bounds__(256) void prep(const float* __restrict__ x,
                                            const float* __restrict__ w_conv,
                                            const float* __restrict__ w_offset,
                                            const float* __restrict__ w_mask,
                                            _Float16* __restrict__ xt,
                                            _Float16* __restrict__ wpk_h,
                                            _Float16* __restrict__ wpk2) {
    __shared__ _Float16 tile[Cin][130];
    int t   = threadIdx.x;
    int bid = blockIdx.x;

    if (bid < 1024) {                       // ---- transpose ----
        int b = bid >> 7;
        int h = bid & 127;
        const float* xb = x + (size_t)b * Cin * HW + (size_t)h * Wimg;
#pragma unroll
        for (int j = 0; j < 32; ++j) {
            int e = t + j * 256;            // 0..8191
            int c = e >> 7;
            int w = e & 127;
            tile[c][w] = (_Float16)xb[(size_t)c * HW + w];
        }
        __syncthreads();
        unsigned* dst = (unsigned*)xt + ((size_t)b * HW + (size_t)h * Wimg) * 32;
#pragma unroll
        for (int j = 0; j < 16; ++j) {
            int d  = t + j * 256;           // 0..4095
            int w  = d >> 5;
            int cp = d & 31;
            union { unsigned u; _Float16 hh[2]; } pk;
            pk.hh[0] = tile[2 * cp][w];
            pk.hh[1] = tile[2 * cp + 1][w];
            dst[d] = pk.u;
        }
        return;
    }

    if (bid < 1024 + 288) {                 // ---- repack main conv weights ----
        int idx = (bid - 1024) * 256 + t;   // 0 .. 73727
        if (idx < Kk * Cin * OUTC) {
            int i    = idx & 7;
            int l    = (idx >> 3) & 63;
            int g    = idx >> 9;            // 0..143
            int mt   = g & 7;
            int ch   = g >> 3;              // 0..17
            int kq   = l >> 4;
            int ln16 = l & 15;
            int o    = mt * 16 + ln16;
            int kl   = kq * 8 + i;
            int c    = (ch & 1) * 32 + kl;
            int kt   = ch >> 1;
            wpk_h[idx] = (_Float16)w_conv[(o * Cin + c) * 9 + kt];
        }
        return;
    }

    {                                       // ---- repack offset/mask weights ----
        int idx = (bid - 1312) * 256 + t;   // 0 .. 18431
        if (idx < 18 * 32 * 32) {
            int i    = idx & 7;
            int l    = (idx >> 3) & 63;
            int g    = idx >> 9;            // 0..35
            int mt0  = g & 1;
            int ch   = g >> 1;              // 0..17
            int kq   = l >> 4;
            int ln16 = l & 15;
            int m    = mt0 * 16 + ln16;
            int kl   = kq * 8 + i;
            int c    = (ch & 1) * 32 + kl;
            int kt   = ch >> 1;
            float v = 0.0f;
            if (m < 18)      v = w_offset[(m * Cin + c) * 9 + kt];
            else if (m < 27) v = w_mask[((m - 18) * Cin + c) * 9 + kt];
            wpk2[idx] = (_Float16)v;
        }
    }
}

// ---------------------------------------------------------------------------
// Fused kernel. Per-wave output decomposition (wave owns all 128 outputs for
// its 16 pixels; V per-wave private LDS, no V barriers). Phase-1 weights are
// staged through LDS once per block per chunk (double-buffered, 8KB/chunk,
// 1 barrier/chunk) instead of each wave re-reading them from L1 (R5: weight
// loads were 2/3 of VMEM instructions and ~half of L1 bytes). Weight LDS
// unions with the dead-after-geometry P buffer -> 26.6 KB/block, 6 blocks/CU.
// Gathers: 2-deep register pipeline. Combine: packed f16.
// __launch_bounds__(256,3): (256,4) caps unified VGPR budget -> scratch (R2/R3).
// ---------------------------------------------------------------------------
__global__ __launch_bounds__(256, 3) void deform_fused(
        const _Float16* __restrict__ xt, const _Float16* __restrict__ wpk_h,
        const _Float16* __restrict__ wpk2,
        const float* __restrict__ b_offset, const float* __restrict__ b_mask,
        float* __restrict__ out) {
    __shared__ _Float16 Vw[4][2][16][40];   // per-wave double-buffered V: 10240 B
    __shared__ union {
        float    P[4][32][16];              //  8192 B (phase0 out, dead after geometry)
        _Float16 Wl[2][4096];               // 16384 B (phase1 weight staging)
    } sm2;                                  // union: 16384 B; total LDS 26624 B

    int t    = threadIdx.x;
    int bid  = blockIdx.x;
    int b    = bid & 7;                      // XCD-batch swizzle
    int pb   = bid >> 3;                     // 0..255
    int pix0 = pb * 64;
    int h    = pix0 >> 7;
    int w0   = pix0 & 127;                   // 0 or 64

    int lane = t & 63;
    int wv   = t >> 6;
    int q    = t >> 2;                       // pixel in slab = wv*16 + (lane>>2)
    int qloc = (lane >> 2) & 15;             // pixel within wave
    int c4   = t & 3;                        // 16B channel-quarter in 32-ch half
    int kq   = lane >> 4;
    int ln16 = lane & 15;

    const _Float16* xtb  = xt + (size_t)b * HW * Cin;
    const half8* wsrc    = (const half8*)wpk_h;
    const half8* w2src   = (const half8*)wpk2;

    // ================= phase 0: offset/mask conv (per-wave) =================
    floatx4 acc2_0 = (floatx4){0.f, 0.f, 0.f, 0.f};
    floatx4 acc2_1 = (floatx4){0.f, 0.f, 0.f, 0.f};

    half8 pvA, pvB, af0p, af1p;

#define LOADX0(chn, DST) { \
    const int ktn = (chn) >> 1, cgn = (chn) & 1; \
    int row = h + (ktn / 3) - 1; \
    int col = w0 + q + (ktn % 3) - 1; \
    bool okc = (row >= 0) && (row < Himg) && (col >= 0) && (col < Wimg); \
    if (okc) DST = *(const half8*)(xtb + ((size_t)(row * Wimg + col)) * Cin \
                                   + cgn * 32 + c4 * 8); \
    else     DST = SPL8((_Float16)0.0f); \
}

#define P0STEP(ch, PV) { \
    half8 af0c = af0p, af1c = af1p; \
    *(half8*)&Vw[wv][(ch) & 1][qloc][c4 * 8] = PV; \
    if ((ch) < 16) LOADX0((ch) + 2, PV); \
    if ((ch) < 17) { \
        af0p = w2src[((size_t)((ch) + 1) * 2 + 0) * 64 + lane]; \
        af1p = w2src[((size_t)((ch) + 1) * 2 + 1) * 64 + lane]; \
    } \
    half8 bf = *(const half8*)&Vw[wv][(ch) & 1][ln16][kq * 8]; \
    acc2_0 = __builtin_amdgcn_mfma_f32_16x16x32_f16(af0c, bf, acc2_0, 0, 0, 0); \
    acc2_1 = __builtin_amdgcn_mfma_f32_16x16x32_f16(af1c, bf, acc2_1, 0, 0, 0); \
}

    LOADX0(0, pvA)
    LOADX0(1, pvB)
    af0p = w2src[(size_t)0 * 64 + lane];
    af1p = w2src[(size_t)1 * 64 + lane];

    P0STEP(0,  pvA) P0STEP(1,  pvB) P0STEP(2,  pvA) P0STEP(3,  pvB)
    P0STEP(4,  pvA) P0STEP(5,  pvB) P0STEP(6,  pvA) P0STEP(7,  pvB)
    P0STEP(8,  pvA) P0STEP(9,  pvB) P0STEP(10, pvA) P0STEP(11, pvB)
    P0STEP(12, pvA) P0STEP(13, pvB) P0STEP(14, pvA) P0STEP(15, pvB)
    P0STEP(16, pvA) P0STEP(17, pvB)

    // conv results -> per-wave P (row m = output chan, col = local pixel)
#pragma unroll
    for (int r = 0; r < 4; ++r) {
        sm2.P[wv][kq * 4 + r][ln16]      = acc2_0[r];
        sm2.P[wv][16 + kq * 4 + r][ln16] = acc2_1[r];
    }

    // ---- per-pixel geometry (pixel q, per-wave P read; no barrier) ----
    // geomr[k] = o00 | dx1<<14 | dy1<<15  (cell index + corner-step flags)
    int      geomr[9];
    unsigned wab[9], wcd[9];                 // f16-packed (w00,w01),(w10,w11)
    {
        float fh = (float)h, fw = (float)(w0 + q);
#pragma unroll
        for (int k = 0; k < 9; ++k) {
            float dyv = sm2.P[wv][2 * k][qloc]     + b_offset[2 * k];
            float dxv = sm2.P[wv][2 * k + 1][qloc] + b_offset[2 * k + 1];
            float mz  = sm2.P[wv][18 + k][qloc]    + b_mask[k];
            float mkv = 1.0f / (1.0f + expf(-mz));

            float gy  = fh + (float)(k / 3) - 1.0f + dyv;
            float gx  = fw + (float)(k % 3) - 1.0f + dxv;
            float y0f = floorf(gy), x0f = floorf(gx);
            int   y0  = (int)y0f,   x0 = (int)x0f;
            float wy  = gy - y0f,   wx = gx - x0f;
            int   y1  = y0 + 1,     x1 = x0 + 1;

            bool vy0 = (y0 >= 0) && (y0 < Himg);
            bool vy1 = (y1 >= 0) && (y1 < Himg);
            bool vx0 = (x0 >= 0) && (x0 < Wimg);
            bool vx1 = (x1 >= 0) && (x1 < Wimg);

            float w00 = (vy0 && vx0) ? (1.0f - wy) * (1.0f - wx) * mkv : 0.0f;
            float w01 = (vy0 && vx1) ? (1.0f - wy) * wx          * mkv : 0.0f;
            float w10 = (vy1 && vx0) ? wy          * (1.0f - wx) * mkv : 0.0f;
            float w11 = (vy1 && vx1) ? wy          * wx          * mkv : 0.0f;

            int y0c = min(max(y0, 0), Himg - 1), y1c = min(max(y1, 0), Himg - 1);
            int x0c = min(max(x0, 0), Wimg - 1), x1c = min(max(x1, 0), Wimg - 1);
            geomr[k] = (y0c * Wimg + x0c) | ((x1c - x0c) << 14) | ((y1c - y0c) << 15);
            union { unsigned u; _Float16 hh[2]; } pk;
            pk.hh[0] = (_Float16)w00; pk.hh[1] = (_Float16)w01; wab[k] = pk.u;
            pk.hh[0] = (_Float16)w10; pk.hh[1] = (_Float16)w11; wcd[k] = pk.u;
        }
    }

    // ================= phase 1: sampling + GEMM =================
    floatx4 acc[8];
#pragma unroll
    for (int i = 0; i < 8; ++i) acc[i] = (floatx4){0.f, 0.f, 0.f, 0.f};

    half8 gA0, gA1, gA2, gA3, gB0, gB1, gB2, gB3, wrA, wrB;

#define LOADG(chn, D0, D1, D2, D3) { \
    int gg = geomr[(chn) >> 1]; \
    const _Float16* xc = xtb + (size_t)(gg & 0x3fff) * Cin \
                         + ((chn) & 1) * 32 + c4 * 8; \
    int ob = (gg & 0x4000) >> 8;   /* dx1*64   */ \
    int oc = (gg & 0x8000) >> 2;   /* dy1*8192 */ \
    D0 = *(const half8*)(xc); \
    D1 = *(const half8*)(xc + ob); \
    D2 = *(const half8*)(xc + oc); \
    D3 = *(const half8*)(xc + oc + ob); \
}

// load chunk chn's 8KB weight block slice for this thread (2 x 16B)
#define LOADW(chn) { \
    wrA = wsrc[(size_t)(chn) * 512 + t]; \
    wrB = wsrc[(size_t)(chn) * 512 + 256 + t]; \
}
// write staged regs into LDS buffer bufi (stride-16B, conflict-free)
#define PUTW(bufi) { \
    *(half8*)&sm2.Wl[bufi][t * 8]        = wrA; \
    *(half8*)&sm2.Wl[bufi][2048 + t * 8] = wrB; \
}

#define P1STEP(ch, G0, G1, G2, G3) { \
    /* stage W(ch+1) into the other buffer (regs loaded during ch-1) */ \
    if ((ch) < 17) PUTW(((ch) + 1) & 1); \
    /* combine current chunk's gathers -> V f16 (packed) */ \
    union { unsigned u; _Float16 hh[2]; } u1, u2; \
    u1.u = wab[(ch) >> 1];  u2.u = wcd[(ch) >> 1]; \
    half8 vv = G0 * SPL8(u1.hh[0]) + G1 * SPL8(u1.hh[1]) \
             + G2 * SPL8(u2.hh[0]) + G3 * SPL8(u2.hh[1]); \
    *(half8*)&Vw[wv][(ch) & 1][qloc][c4 * 8] = vv; \
    /* prefetch gathers + weight block for ch+2 */ \
    if ((ch) < 16) LOADG((ch) + 2, G0, G1, G2, G3); \
    if ((ch) < 16) LOADW((ch) + 2); \
    /* consume: V (own wave's) + 8 staged A-fragments */ \
    half8 bf = *(const half8*)&Vw[wv][(ch) & 1][ln16][kq * 8]; \
    half8 a0 = *(const half8*)&sm2.Wl[(ch) & 1][0 * 512 + lane * 8]; \
    half8 a1 = *(const half8*)&sm2.Wl[(ch) & 1][1 * 512 + lane * 8]; \
    half8 a2 = *(const half8*)&sm2.Wl[(ch) & 1][2 * 512 + lane * 8]; \
    half8 a3 = *(const half8*)&sm2.Wl[(ch) & 1][3 * 512 + lane * 8]; \
    half8 a4 = *(const half8*)&sm2.Wl[(ch) & 1][4 * 512 + lane * 8]; \
    half8 a5 = *(const half8*)&sm2.Wl[(ch) & 1][5 * 512 + lane * 8]; \
    half8 a6 = *(const half8*)&sm2.Wl[(ch) & 1][6 * 512 + lane * 8]; \
    half8 a7 = *(const half8*)&sm2.Wl[(ch) & 1][7 * 512 + lane * 8]; \
    acc[0] = __builtin_amdgcn_mfma_f32_16x16x32_f16(a0, bf, acc[0], 0, 0, 0); \
    acc[1] = __builtin_amdgcn_mfma_f32_16x16x32_f16(a1, bf, acc[1], 0, 0, 0); \
    acc[2] = __builtin_amdgcn_mfma_f32_16x16x32_f16(a2, bf, acc[2], 0, 0, 0); \
    acc[3] = __builtin_amdgcn_mfma_f32_16x16x32_f16(a3, bf, acc[3], 0, 0, 0); \
    acc[4] = __builtin_amdgcn_mfma_f32_16x16x32_f16(a4, bf, acc[4], 0, 0, 0); \
    acc[5] = __builtin_amdgcn_mfma_f32_16x16x32_f16(a5, bf, acc[5], 0, 0, 0); \
    acc[6] = __builtin_amdgcn_mfma_f32_16x16x32_f16(a6, bf, acc[6], 0, 0, 0); \
    acc[7] = __builtin_amdgcn_mfma_f32_16x16x32_f16(a7, bf, acc[7], 0, 0, 0); \
    __syncthreads();   /* buf (ch+2)&1 == ch&1 safe to overwrite next step */ \
}

    __syncthreads();                  // all waves done reading P (union w/ Wl)

    // W prologue: stage chunk 0 directly, preload chunk 1 into regs
    LOADW(0)
    PUTW(0)
    LOADW(1)
    // gather prologue
    LOADG(0, gA0, gA1, gA2, gA3)
    LOADG(1, gB0, gB1, gB2, gB3)
    __syncthreads();                  // Wl buf0 visible to all waves

    P1STEP(0,  gA0, gA1, gA2, gA3) P1STEP(1,  gB0, gB1, gB2, gB3)
    P1STEP(2,  gA0, gA1, gA2, gA3) P1STEP(3,  gB0, gB1, gB2, gB3)
    P1STEP(4,  gA0, gA1, gA2, gA3) P1STEP(5,  gB0, gB1, gB2, gB3)
    P1STEP(6,  gA0, gA1, gA2, gA3) P1STEP(7,  gB0, gB1, gB2, gB3)
    P1STEP(8,  gA0, gA1, gA2, gA3) P1STEP(9,  gB0, gB1, gB2, gB3)
    P1STEP(10, gA0, gA1, gA2, gA3) P1STEP(11, gB0, gB1, gB2, gB3)
    P1STEP(12, gA0, gA1, gA2, gA3) P1STEP(13, gB0, gB1, gB2, gB3)
    P1STEP(14, gA0, gA1, gA2, gA3) P1STEP(15, gB0, gB1, gB2, gB3)
    P1STEP(16, gA0, gA1, gA2, gA3) P1STEP(17, gB0, gB1, gB2, gB3)

    // epilogue: D col=ln16 (local pixel), row=(kq*4+r) within m-tile mt
#pragma unroll
    for (int mt = 0; mt < 8; ++mt) {
#pragma unroll
        for (int r = 0; r < 4; ++r) {
            int o = mt * 16 + kq * 4 + r;
            out[(size_t)(b * OUTC + o) * HW + pix0 + wv * 16 + ln16] = acc[mt][r];
        }
    }
}

// ---------------------------------------------------------------------------
extern "C" void kernel_launch(void* const* d_in, const int* in_sizes, int n_in,
                              void* d_out, int out_size, void* d_ws, size_t ws_size,
                              hipStream_t stream) {
    const float* x        = (const float*)d_in[0];
    const float* w_offset = (const float*)d_in[1];
    const float* b_offset = (const float*)d_in[2];
    const float* w_mask   = (const float*)d_in[3];
    const float* b_mask   = (const float*)d_in[4];
    const float* w_conv   = (const float*)d_in[5];
    float* out = (float*)d_out;

    _Float16* wpk_h = (_Float16*)d_ws;                   // 73,728 halves
    _Float16* wpk2  = wpk_h + 73728;                     // 18,432 halves
    _Float16* xtb   = wpk2 + 18432;                      // 8,388,608 halves (16.8 MB)

    prep<<<1384, 256, 0, stream>>>(x, w_conv, w_offset, w_mask, xtb, wpk_h, wpk2);
    deform_fused<<<2048, 256, 0, stream>>>(xtb, wpk_h, wpk2, b_offset, b_mask, out);
}

// Round 7
// 156.840 us; speedup vs baseline: 1.2849x; 1.2849x over previous
//
#include <hip/hip_runtime.h>
#include <math.h>

#define Himg 128
#define Wimg 128
#define HW   16384      // 128*128
#define Cin  64
#define Kk   9
#define OUTC 128
#define Bsz  8

typedef __attribute__((ext_vector_type(8))) _Float16 half8;
typedef __attribute__((ext_vector_type(4))) float   floatx4;
typedef __attribute__((ext_vector_type(4))) int     intx4;

#define SPL8(v) ((half8){(v),(v),(v),(v),(v),(v),(v),(v)})

// ---------------------------------------------------------------------------
// fused prep kernel (unchanged layouts):
//   blocks    0..1023 : transpose+convert x[b][c][h][w] f32 -> xt[b][h][w][c] f16
//   blocks 1024..1311 : repack w_conv into MFMA-fragment order (wpk_h)
//   blocks 1312..1383 : repack w_offset/w_mask into fragment order (wpk2)
// ---------------------------------------------------------------------------
__global__ __launch_bounds__(256) void prep(const float* __restrict__ x,
                                            const float* __restrict__ w_conv,
                                            const float* __restrict__ w_offset,
                                            const float* __restrict__ w_mask,
                                            _Float16* __restrict__ xt,
                                            _Float16* __restrict__ wpk_h,
                                            _Float16* __restrict__ wpk2) {
    __shared__ _Float16 tile[Cin][130];
    int t   = threadIdx.x;
    int bid = blockIdx.x;

    if (bid < 1024) {                       // ---- transpose ----
        int b = bid >> 7;
        int h = bid & 127;
        const float* xb = x + (size_t)b * Cin * HW + (size_t)h * Wimg;
#pragma unroll
        for (int j = 0; j < 32; ++j) {
            int e = t + j * 256;            // 0..8191
            int c = e >> 7;
            int w = e & 127;
            tile[c][w] = (_Float16)xb[(size_t)c * HW + w];
        }
        __syncthreads();
        unsigned* dst = (unsigned*)xt + ((size_t)b * HW + (size_t)h * Wimg) * 32;
#pragma unroll
        for (int j = 0; j < 16; ++j) {
            int d  = t + j * 256;           // 0..4095
            int w  = d >> 5;
            int cp = d & 31;
            union { unsigned u; _Float16 hh[2]; } pk;
            pk.hh[0] = tile[2 * cp][w];
            pk.hh[1] = tile[2 * cp + 1][w];
            dst[d] = pk.u;
        }
        return;
    }

    if (bid < 1024 + 288) {                 // ---- repack main conv weights ----
        int idx = (bid - 1024) * 256 + t;   // 0 .. 73727
        if (idx < Kk * Cin * OUTC) {
            int i    = idx & 7;
            int l    = (idx >> 3) & 63;
            int g    = idx >> 9;            // 0..143
            int mt   = g & 7;
            int ch   = g >> 3;              // 0..17
            int kq   = l >> 4;
            int ln16 = l & 15;
            int o    = mt * 16 + ln16;
            int kl   = kq * 8 + i;
            int c    = (ch & 1) * 32 + kl;
            int kt   = ch >> 1;
            wpk_h[idx] = (_Float16)w_conv[(o * Cin + c) * 9 + kt];
        }
        return;
    }

    {                                       // ---- repack offset/mask weights ----
        int idx = (bid - 1312) * 256 + t;   // 0 .. 18431
        if (idx < 18 * 32 * 32) {
            int i    = idx & 7;
            int l    = (idx >> 3) & 63;
            int g    = idx >> 9;            // 0..35
            int mt0  = g & 1;
            int ch   = g >> 1;              // 0..17
            int kq   = l >> 4;
            int ln16 = l & 15;
            int m    = mt0 * 16 + ln16;
            int kl   = kq * 8 + i;
            int c    = (ch & 1) * 32 + kl;
            int kt   = ch >> 1;
            float v = 0.0f;
            if (m < 18)      v = w_offset[(m * Cin + c) * 9 + kt];
            else if (m < 27) v = w_mask[((m - 18) * Cin + c) * 9 + kt];
            wpk2[idx] = (_Float16)v;
        }
    }
}

// ---------------------------------------------------------------------------
// Fused kernel, barrier-free per-wave decomposition, 32 px/wave.
// Wave owns ALL 128 outputs for 32 pixels (two 16-px groups G0/G1) -> each
// chunk's 8 weight A-fragments (8KB) are loaded ONCE per wave and reused by
// both groups' MFMAs: weight VMEM per pixel is HALF of R5. V tiles stay
// per-wave private LDS; per-pixel geometry lives in per-wave LDS (Geo int4,
// one b128 read per group per chunk). ZERO __syncthreads in the kernel.
// Gathers: 2-deep register pipeline per group, named regs only.
// __launch_bounds__(256,2): acc 64 + gather 64 + weight 32 VGPR needs the
// 256-cap; (256,3)'s 170-cap would spill (R2/R3 lesson: spill => scratch).
// ---------------------------------------------------------------------------
__global__ __launch_bounds__(256, 2) void deform_fused(
        const _Float16* __restrict__ xt, const _Float16* __restrict__ wpk_h,
        const _Float16* __restrict__ wpk2,
        const float* __restrict__ b_offset, const float* __restrict__ b_mask,
        float* __restrict__ out) {
    __shared__ _Float16 Vw[4][2][32][40];   // per-wave dbuf V (2 groups): 20480 B
    __shared__ float    Pw[4][32][32];      // per-wave conv outputs:      16384 B
    __shared__ int      Geo[4][9][32][4];   // per-wave geometry int4:     18432 B

    int t    = threadIdx.x;
    int bid  = blockIdx.x;
    int b    = bid & 7;                      // XCD-batch swizzle
    int pb   = bid >> 3;                     // 0..127  (= image row h)
    int pix0 = pb << 7;                      // 128 px per block: one full row
    int h    = pb;

    int lane = t & 63;
    int wv   = t >> 6;
    int qloc = lane >> 2;                    // pixel-in-group 0..15
    int c4   = lane & 3;                     // 16B channel-quarter
    int kq   = lane >> 4;
    int ln16 = lane & 15;
    int sp0  = wv * 32;                      // wave's pixel base within row

    const _Float16* xtb  = xt + (size_t)b * HW * Cin;
    const half8* wsrc    = (const half8*)wpk_h;
    const half8* w2src   = (const half8*)wpk2;

    // ================= phase 0: offset/mask conv (per-wave, 32 px) ==========
    floatx4 acc2_00 = (floatx4){0.f,0.f,0.f,0.f};   // mt0 x G0
    floatx4 acc2_10 = (floatx4){0.f,0.f,0.f,0.f};   // mt1 x G0
    floatx4 acc2_01 = (floatx4){0.f,0.f,0.f,0.f};   // mt0 x G1
    floatx4 acc2_11 = (floatx4){0.f,0.f,0.f,0.f};   // mt1 x G1

    half8 pvA0, pvB0, pvA1, pvB1, af0p, af1p;

#define LOADX0(chn, g, DST) { \
    const int ktn = (chn) >> 1, cgn = (chn) & 1; \
    int row = h + (ktn / 3) - 1; \
    int col = sp0 + (g) * 16 + qloc + (ktn % 3) - 1; \
    bool okc = (row >= 0) && (row < Himg) && (col >= 0) && (col < Wimg); \
    if (okc) DST = *(const half8*)(xtb + ((size_t)(row * Wimg + col)) * Cin \
                                   + cgn * 32 + c4 * 8); \
    else     DST = SPL8((_Float16)0.0f); \
}

#define P0STEP(ch, PV0, PV1) { \
    half8 af0c = af0p, af1c = af1p; \
    *(half8*)&Vw[wv][(ch) & 1][qloc][c4 * 8]      = PV0; \
    *(half8*)&Vw[wv][(ch) & 1][16 + qloc][c4 * 8] = PV1; \
    if ((ch) < 16) { LOADX0((ch) + 2, 0, PV0) LOADX0((ch) + 2, 1, PV1) } \
    if ((ch) < 17) { \
        af0p = w2src[((size_t)((ch) + 1) * 2 + 0) * 64 + lane]; \
        af1p = w2src[((size_t)((ch) + 1) * 2 + 1) * 64 + lane]; \
    } \
    half8 bf0 = *(const half8*)&Vw[wv][(ch) & 1][ln16][kq * 8]; \
    half8 bf1 = *(const half8*)&Vw[wv][(ch) & 1][16 + ln16][kq * 8]; \
    acc2_00 = __builtin_amdgcn_mfma_f32_16x16x32_f16(af0c, bf0, acc2_00, 0, 0, 0); \
    acc2_10 = __builtin_amdgcn_mfma_f32_16x16x32_f16(af1c, bf0, acc2_10, 0, 0, 0); \
    acc2_01 = __builtin_amdgcn_mfma_f32_16x16x32_f16(af0c, bf1, acc2_01, 0, 0, 0); \
    acc2_11 = __builtin_amdgcn_mfma_f32_16x16x32_f16(af1c, bf1, acc2_11, 0, 0, 0); \
}

    LOADX0(0, 0, pvA0) LOADX0(0, 1, pvA1)
    LOADX0(1, 0, pvB0) LOADX0(1, 1, pvB1)
    af0p = w2src[(size_t)0 * 64 + lane];
    af1p = w2src[(size_t)1 * 64 + lane];

    P0STEP(0,  pvA0, pvA1) P0STEP(1,  pvB0, pvB1)
    P0STEP(2,  pvA0, pvA1) P0STEP(3,  pvB0, pvB1)
    P0STEP(4,  pvA0, pvA1) P0STEP(5,  pvB0, pvB1)
    P0STEP(6,  pvA0, pvA1) P0STEP(7,  pvB0, pvB1)
    P0STEP(8,  pvA0, pvA1) P0STEP(9,  pvB0, pvB1)
    P0STEP(10, pvA0, pvA1) P0STEP(11, pvB0, pvB1)
    P0STEP(12, pvA0, pvA1) P0STEP(13, pvB0, pvB1)
    P0STEP(14, pvA0, pvA1) P0STEP(15, pvB0, pvB1)
    P0STEP(16, pvA0, pvA1) P0STEP(17, pvB0, pvB1)

    // conv results -> per-wave P  (row m = conv chan, col = pixel 0..31)
#pragma unroll
    for (int r = 0; r < 4; ++r) {
        Pw[wv][kq * 4 + r][ln16]           = acc2_00[r];
        Pw[wv][16 + kq * 4 + r][ln16]      = acc2_10[r];
        Pw[wv][kq * 4 + r][16 + ln16]      = acc2_01[r];
        Pw[wv][16 + kq * 4 + r][16 + ln16] = acc2_11[r];
    }

    // ---- per-pixel geometry -> per-wave LDS (lane pair per pixel) ----
    {
        int pxg = lane >> 1;                 // 0..31
        float fh = (float)h, fw = (float)(sp0 + pxg);
#pragma unroll
        for (int k = 0; k < 9; ++k) {
            float dyv = Pw[wv][2 * k][pxg]     + b_offset[2 * k];
            float dxv = Pw[wv][2 * k + 1][pxg] + b_offset[2 * k + 1];
            float mz  = Pw[wv][18 + k][pxg]    + b_mask[k];
            float mkv = 1.0f / (1.0f + expf(-mz));

            float gy  = fh + (float)(k / 3) - 1.0f + dyv;
            float gx  = fw + (float)(k % 3) - 1.0f + dxv;
            float y0f = floorf(gy), x0f = floorf(gx);
            int   y0  = (int)y0f,   x0 = (int)x0f;
            float wy  = gy - y0f,   wx = gx - x0f;
            int   y1  = y0 + 1,     x1 = x0 + 1;

            bool vy0 = (y0 >= 0) && (y0 < Himg);
            bool vy1 = (y1 >= 0) && (y1 < Himg);
            bool vx0 = (x0 >= 0) && (x0 < Wimg);
            bool vx1 = (x1 >= 0) && (x1 < Wimg);

            float w00 = (vy0 && vx0) ? (1.0f - wy) * (1.0f - wx) * mkv : 0.0f;
            float w01 = (vy0 && vx1) ? (1.0f - wy) * wx          * mkv : 0.0f;
            float w10 = (vy1 && vx0) ? wy          * (1.0f - wx) * mkv : 0.0f;
            float w11 = (vy1 && vx1) ? wy          * wx          * mkv : 0.0f;

            int y0c = min(max(y0, 0), Himg - 1), y1c = min(max(y1, 0), Himg - 1);
            int x0c = min(max(x0, 0), Wimg - 1), x1c = min(max(x1, 0), Wimg - 1);
            int geom = (y0c * Wimg + x0c) | ((x1c - x0c) << 14) | ((y1c - y0c) << 15);
            union { unsigned u; _Float16 hh[2]; } pk;
            int wabk, wcdk;
            pk.hh[0] = (_Float16)w00; pk.hh[1] = (_Float16)w01; wabk = (int)pk.u;
            pk.hh[0] = (_Float16)w10; pk.hh[1] = (_Float16)w11; wcdk = (int)pk.u;
            if ((lane & 1) == 0) {
                Geo[wv][k][pxg][0] = geom;
                Geo[wv][k][pxg][1] = wabk;
                Geo[wv][k][pxg][2] = wcdk;
            }
        }
    }

    // ================= phase 1: sampling + GEMM (per-wave, 32 px) ===========
    floatx4 acc[8][2];
#pragma unroll
    for (int i = 0; i < 8; ++i) {
        acc[i][0] = (floatx4){0.f,0.f,0.f,0.f};
        acc[i][1] = (floatx4){0.f,0.f,0.f,0.f};
    }

    half8 gA0, gA1, gA2, gA3;   // G0 even-chunk set
    half8 gB0, gB1, gB2, gB3;   // G0 odd-chunk set
    half8 gC0, gC1, gC2, gC3;   // G1 even-chunk set
    half8 gD0, gD1, gD2, gD3;   // G1 odd-chunk set

#define LOADG(chn, g, D0, D1, D2, D3) { \
    int gg = Geo[wv][(chn) >> 1][(g) * 16 + qloc][0]; \
    const _Float16* xc = xtb + (size_t)(gg & 0x3fff) * Cin \
                         + ((chn) & 1) * 32 + c4 * 8; \
    int ob = (gg & 0x4000) >> 8;   /* dx1*64   */ \
    int oc = (gg & 0x8000) >> 2;   /* dy1*8192 */ \
    D0 = *(const half8*)(xc); \
    D1 = *(const half8*)(xc + ob); \
    D2 = *(const half8*)(xc + oc); \
    D3 = *(const half8*)(xc + oc + ob); \
}

#define P1STEP(ch, A0, A1, A2, A3, C0, C1, C2, C3) { \
    /* this chunk's 8 weight fragments: issue first, consume last */ \
    half8 w_0 = wsrc[((size_t)(ch) * 8 + 0) * 64 + lane]; \
    half8 w_1 = wsrc[((size_t)(ch) * 8 + 1) * 64 + lane]; \
    half8 w_2 = wsrc[((size_t)(ch) * 8 + 2) * 64 + lane]; \
    half8 w_3 = wsrc[((size_t)(ch) * 8 + 3) * 64 + lane]; \
    half8 w_4 = wsrc[((size_t)(ch) * 8 + 4) * 64 + lane]; \
    half8 w_5 = wsrc[((size_t)(ch) * 8 + 5) * 64 + lane]; \
    half8 w_6 = wsrc[((size_t)(ch) * 8 + 6) * 64 + lane]; \
    half8 w_7 = wsrc[((size_t)(ch) * 8 + 7) * 64 + lane]; \
    /* combine weights for this chunk (per-wave LDS, b128) */ \
    intx4 q0 = *(const intx4*)&Geo[wv][(ch) >> 1][qloc][0]; \
    intx4 q1 = *(const intx4*)&Geo[wv][(ch) >> 1][16 + qloc][0]; \
    union { unsigned u; _Float16 hh[2]; } u1, u2; \
    u1.u = (unsigned)q0.y;  u2.u = (unsigned)q0.z; \
    half8 vv0 = A0 * SPL8(u1.hh[0]) + A1 * SPL8(u1.hh[1]) \
              + A2 * SPL8(u2.hh[0]) + A3 * SPL8(u2.hh[1]); \
    *(half8*)&Vw[wv][(ch) & 1][qloc][c4 * 8] = vv0; \
    u1.u = (unsigned)q1.y;  u2.u = (unsigned)q1.z; \
    half8 vv1 = C0 * SPL8(u1.hh[0]) + C1 * SPL8(u1.hh[1]) \
              + C2 * SPL8(u2.hh[0]) + C3 * SPL8(u2.hh[1]); \
    *(half8*)&Vw[wv][(ch) & 1][16 + qloc][c4 * 8] = vv1; \
    /* prefetch chunk ch+2's gathers into the just-freed sets */ \
    if ((ch) < 16) { \
        LOADG((ch) + 2, 0, A0, A1, A2, A3) \
        LOADG((ch) + 2, 1, C0, C1, C2, C3) \
    } \
    half8 bf0 = *(const half8*)&Vw[wv][(ch) & 1][ln16][kq * 8]; \
    half8 bf1 = *(const half8*)&Vw[wv][(ch) & 1][16 + ln16][kq * 8]; \
    acc[0][0] = __builtin_amdgcn_mfma_f32_16x16x32_f16(w_0, bf0, acc[0][0], 0, 0, 0); \
    acc[1][0] = __builtin_amdgcn_mfma_f32_16x16x32_f16(w_1, bf0, acc[1][0], 0, 0, 0); \
    acc[2][0] = __builtin_amdgcn_mfma_f32_16x16x32_f16(w_2, bf0, acc[2][0], 0, 0, 0); \
    acc[3][0] = __builtin_amdgcn_mfma_f32_16x16x32_f16(w_3, bf0, acc[3][0], 0, 0, 0); \
    acc[4][0] = __builtin_amdgcn_mfma_f32_16x16x32_f16(w_4, bf0, acc[4][0], 0, 0, 0); \
    acc[5][0] = __builtin_amdgcn_mfma_f32_16x16x32_f16(w_5, bf0, acc[5][0], 0, 0, 0); \
    acc[6][0] = __builtin_amdgcn_mfma_f32_16x16x32_f16(w_6, bf0, acc[6][0], 0, 0, 0); \
    acc[7][0] = __builtin_amdgcn_mfma_f32_16x16x32_f16(w_7, bf0, acc[7][0], 0, 0, 0); \
    acc[0][1] = __builtin_amdgcn_mfma_f32_16x16x32_f16(w_0, bf1, acc[0][1], 0, 0, 0); \
    acc[1][1] = __builtin_amdgcn_mfma_f32_16x16x32_f16(w_1, bf1, acc[1][1], 0, 0, 0); \
    acc[2][1] = __builtin_amdgcn_mfma_f32_16x16x32_f16(w_2, bf1, acc[2][1], 0, 0, 0); \
    acc[3][1] = __builtin_amdgcn_mfma_f32_16x16x32_f16(w_3, bf1, acc[3][1], 0, 0, 0); \
    acc[4][1] = __builtin_amdgcn_mfma_f32_16x16x32_f16(w_4, bf1, acc[4][1], 0, 0, 0); \
    acc[5][1] = __builtin_amdgcn_mfma_f32_16x16x32_f16(w_5, bf1, acc[5][1], 0, 0, 0); \
    acc[6][1] = __builtin_amdgcn_mfma_f32_16x16x32_f16(w_6, bf1, acc[6][1], 0, 0, 0); \
    acc[7][1] = __builtin_amdgcn_mfma_f32_16x16x32_f16(w_7, bf1, acc[7][1], 0, 0, 0); \
}

    // prologue: prefetch gather chunks 0,1 for both groups
    LOADG(0, 0, gA0, gA1, gA2, gA3)
    LOADG(0, 1, gC0, gC1, gC2, gC3)
    LOADG(1, 0, gB0, gB1, gB2, gB3)
    LOADG(1, 1, gD0, gD1, gD2, gD3)

    P1STEP(0,  gA0, gA1, gA2, gA3, gC0, gC1, gC2, gC3)
    P1STEP(1,  gB0, gB1, gB2, gB3, gD0, gD1, gD2, gD3)
    P1STEP(2,  gA0, gA1, gA2, gA3, gC0, gC1, gC2, gC3)
    P1STEP(3,  gB0, gB1, gB2, gB3, gD0, gD1, gD2, gD3)
    P1STEP(4,  gA0, gA1, gA2, gA3, gC0, gC1, gC2, gC3)
    P1STEP(5,  gB0, gB1, gB2, gB3, gD0, gD1, gD2, gD3)
    P1STEP(6,  gA0, gA1, gA2, gA3, gC0, gC1, gC2, gC3)
    P1STEP(7,  gB0, gB1, gB2, gB3, gD0, gD1, gD2, gD3)
    P1STEP(8,  gA0, gA1, gA2, gA3, gC0, gC1, gC2, gC3)
    P1STEP(9,  gB0, gB1, gB2, gB3, gD0, gD1, gD2, gD3)
    P1STEP(10, gA0, gA1, gA2, gA3, gC0, gC1, gC2, gC3)
    P1STEP(11, gB0, gB1, gB2, gB3, gD0, gD1, gD2, gD3)
    P1STEP(12, gA0, gA1, gA2, gA3, gC0, gC1, gC2, gC3)
    P1STEP(13, gB0, gB1, gB2, gB3, gD0, gD1, gD2, gD3)
    P1STEP(14, gA0, gA1, gA2, gA3, gC0, gC1, gC2, gC3)
    P1STEP(15, gB0, gB1, gB2, gB3, gD0, gD1, gD2, gD3)
    P1STEP(16, gA0, gA1, gA2, gA3, gC0, gC1, gC2, gC3)
    P1STEP(17, gB0, gB1, gB2, gB3, gD0, gD1, gD2, gD3)

    // epilogue: D col=ln16 (pixel in group), row=kq*4+r within m-tile
#pragma unroll
    for (int mt = 0; mt < 8; ++mt) {
#pragma unroll
        for (int g = 0; g < 2; ++g) {
#pragma unroll
            for (int r = 0; r < 4; ++r) {
                int o = mt * 16 + kq * 4 + r;
                out[(size_t)(b * OUTC + o) * HW + pix0 + sp0 + g * 16 + ln16]
                    = acc[mt][g][r];
            }
        }
    }
}

// ---------------------------------------------------------------------------
extern "C" void kernel_launch(void* const* d_in, const int* in_sizes, int n_in,
                              void* d_out, int out_size, void* d_ws, size_t ws_size,
                              hipStream_t stream) {
    const float* x        = (const float*)d_in[0];
    const float* w_offset = (const float*)d_in[1];
    const float* b_offset = (const float*)d_in[2];
    const float* w_mask   = (const float*)d_in[3];
    const float* b_mask   = (const float*)d_in[4];
    const float* w_conv   = (const float*)d_in[5];
    float* out = (float*)d_out;

    _Float16* wpk_h = (_Float16*)d_ws;                   // 73,728 halves
    _Float16* wpk2  = wpk_h + 73728;                     // 18,432 halves
    _Float16* xtb   = wpk2 + 18432;                      // 8,388,608 halves (16.8 MB)

    prep<<<1384, 256, 0, stream>>>(x, w_conv, w_offset, w_mask, xtb, wpk_h, wpk2);
    deform_fused<<<1024, 256, 0, stream>>>(xtb, wpk_h, wpk2, b_offset, b_mask, out);
}